// Round 14
// baseline (88.513 us; speedup 1.0000x reference)
//
#include <hip/hip_runtime.h>
#include <hip/hip_bf16.h>

typedef __attribute__((ext_vector_type(4))) float f32x4;
typedef __attribute__((ext_vector_type(16))) float f32x16;
typedef __attribute__((ext_vector_type(8))) short bf16x8;

#define NH 8
#define HD 64
#define WSZ 128
#define DM 512

typedef __attribute__((address_space(3))) void lds_t;
typedef const __attribute__((address_space(1))) void gbl_t;

__device__ __forceinline__ unsigned int pk2bf(float lo, float hi) {
    union { __hip_bfloat162 h; unsigned int u; } r;
    r.h = __float22bfloat162_rn(make_float2(lo, hi));
    return r.u;
}

__device__ __forceinline__ bf16x8 pack8(f32x4 a, f32x4 b) {
    union { unsigned int u[4]; bf16x8 v; } r;
    r.u[0] = pk2bf(a[0], a[1]);
    r.u[1] = pk2bf(a[2], a[3]);
    r.u[2] = pk2bf(b[0], b[1]);
    r.u[3] = pk2bf(b[2], b[3]);
    return r.v;
}

// One block = one (batch, window, head). 4 waves, each owns 32 q-columns of S^T.
// 32x32x16 MFMA; swapped QK^T -> S^T (lane-local softmax); P via
// cvt_pk + v_permlane32_swap (no LDS for P).
// KEY CHANGE vs r13: K and V staged as fp32 via global_load_lds (fire-and-
// forget, zero VGPR, unsinkable): 16 x 1KB per wave in flight back-to-back.
// K: linear LDS dest + inverse-swizzled GLOBAL source (granule gs holds
// global granule gs^(row&15)); read applies same XOR -> no 32-way conflicts.
// V: plain linear [k][d]; PV B-fragment = 8x ds_read_b32 at bank=c
// (conflict-free) + cvt_pk, eliminating the register transpose entirely.
// fp32->bf16 conversion moves to fragment-read time (same cvt count).
__global__ __launch_bounds__(256, 2) void wattn_kernel(
    const float* __restrict__ q1, const float* __restrict__ k1,
    const float* __restrict__ v1, float* __restrict__ o1, int nw1,
    const float* __restrict__ q2, const float* __restrict__ k2,
    const float* __restrict__ v2, float* __restrict__ o2, int nw2,
    int nblk1)
{
    __shared__ __align__(16) float Kl[128 * 64];   // fp32, granule-swizzled
    __shared__ __align__(16) float Vl[128 * 64];   // fp32, linear row-major

    const int t = threadIdx.x;
    const int lane = t & 63;
    const int wid = t >> 6;
    const int hi = lane >> 5;   // 0..1
    const int c = lane & 31;    // 0..31

    int bid = blockIdx.x;
    const float *q, *k, *v; float* o; int nw;
    if (bid < nblk1) { q = q1; k = k1; v = v1; o = o1; nw = nw1; }
    else { bid -= nblk1; q = q2; k = k2; v = v2; o = o2; nw = nw2; }

    const int h = bid & (NH - 1);
    const int w = (bid / NH) % nw;
    const int b = (bid / NH) / nw;

    const size_t row0 = ((size_t)b * nw + w) * WSZ;
    const float* Qp = q + row0 * DM + h * HD;
    const float* Kp = k + row0 * DM + h * HD;
    const float* Vp = v + row0 * DM + h * HD;
    float* Op = o + row0 * DM + h * HD;

    const int qbase = wid * 32;

    // ===== stage K,V via global_load_lds: 8+8 instrs/wave, fire-and-forget =====
    // instr idx covers LDS 16B-granules [idx*64, idx*64+64): lane l -> granule
    // idx*64+l -> row = idx*4 + (l>>4), gs = l&15. K source granule = gs^(row&15).
#pragma unroll
    for (int ii = 0; ii < 8; ++ii) {
        const int idx = wid * 8 + ii;
        const int row = idx * 4 + (lane >> 4);
        const int gs = lane & 15;
        const float* gk = Kp + (size_t)row * DM + ((gs ^ (row & 15)) << 2);
        const float* gv = Vp + (size_t)row * DM + (gs << 2);
        __builtin_amdgcn_global_load_lds((gbl_t*)gk,
            (lds_t*)((char*)Kl + idx * 1024), 16, 0, 0);
        __builtin_amdgcn_global_load_lds((gbl_t*)gv,
            (lds_t*)((char*)Vl + idx * 1024), 16, 0, 0);
    }

    // ---- Q fragments direct from global (B-operand: q=qbase+c, d=ks*16+hi*8+j) ----
    bf16x8 qf[4];
#pragma unroll
    for (int ks = 0; ks < 4; ++ks) {
        const float* src = Qp + (size_t)(qbase + c) * DM + ks * 16 + hi * 8;
        f32x4 a = *reinterpret_cast<const f32x4*>(src);
        f32x4 bq = *reinterpret_cast<const f32x4*>(src + 4);
        qf[ks] = pack8(a, bq);
    }

    __syncthreads();   // drains vmcnt (incl. global_load_lds) + barrier

    // ---- S^T = K Q^T : acc[mf], D: col=c (q), row k = mf*32+(reg&3)+8*(reg>>2)+4*hi
    f32x16 acc[4] = {};
#pragma unroll
    for (int ks = 0; ks < 4; ++ks) {
#pragma unroll
        for (int mf = 0; mf < 4; ++mf) {
            const int row = mf * 32 + c;
            const int r15 = c & 15;          // row & 15
            const int g0 = ks * 4 + hi * 2;  // first 16B granule of the 32B frag
            f32x4 a = *reinterpret_cast<const f32x4*>(&Kl[row * 64 + ((g0 ^ r15) << 2)]);
            f32x4 bq = *reinterpret_cast<const f32x4*>(&Kl[row * 64 + (((g0 + 1) ^ r15) << 2)]);
            const bf16x8 kf = pack8(a, bq);
            acc[mf] = __builtin_amdgcn_mfma_f32_32x32x16_bf16(kf, qf[ks], acc[mf], 0, 0, 0);
        }
    }

    // ---- softmax over k: lane-local, tree-reduced, one cross-half shfl ----
    const float CEXP = 0.125f * 1.4426950408889634f;
    float mxa = fmaxf(acc[0][0], acc[1][0]);
    float mxb = fmaxf(acc[2][0], acc[3][0]);
#pragma unroll
    for (int e = 1; e < 16; ++e) {
        mxa = fmaxf(mxa, fmaxf(acc[0][e], acc[1][e]));
        mxb = fmaxf(mxb, fmaxf(acc[2][e], acc[3][e]));
    }
    float mx = fmaxf(mxa, mxb);
    mx = fmaxf(mx, __shfl_xor(mx, 32));
    const float mxc = mx * CEXP;
    float s0 = 0.f, s1 = 0.f, s2 = 0.f, s3 = 0.f;
#pragma unroll
    for (int e = 0; e < 16; ++e) {
        float p0 = exp2f(acc[0][e] * CEXP - mxc);
        float p1 = exp2f(acc[1][e] * CEXP - mxc);
        float p2 = exp2f(acc[2][e] * CEXP - mxc);
        float p3 = exp2f(acc[3][e] * CEXP - mxc);
        acc[0][e] = p0; acc[1][e] = p1; acc[2][e] = p2; acc[3][e] = p3;
        s0 += p0; s1 += p1; s2 += p2; s3 += p3;
    }
    float sum = (s0 + s1) + (s2 + s3);
    sum += __shfl_xor(sum, 32);
    const float rinv = 1.0f / sum;

    // ---- O = P V : pack P + permlane32_swap -> A-frag; V B-frag = 8x b32 + cvt ----
    f32x16 oacc[2] = {};
#pragma unroll
    for (int f = 0; f < 4; ++f) {
#pragma unroll
        for (int p = 0; p < 2; ++p) {
            const int kb2 = f * 2 + p;
            unsigned int U0 = pk2bf(acc[f][8 * p + 0], acc[f][8 * p + 1]);
            unsigned int U1 = pk2bf(acc[f][8 * p + 2], acc[f][8 * p + 3]);
            unsigned int U2 = pk2bf(acc[f][8 * p + 4], acc[f][8 * p + 5]);
            unsigned int U3 = pk2bf(acc[f][8 * p + 6], acc[f][8 * p + 7]);
            asm volatile("v_permlane32_swap_b32 %0, %1" : "+v"(U0), "+v"(U2));
            asm volatile("v_permlane32_swap_b32 %0, %1" : "+v"(U1), "+v"(U3));
            union { unsigned int u[4]; bf16x8 v; } A;
            A.u[0] = U0; A.u[1] = U1; A.u[2] = U2; A.u[3] = U3;
            const int k0 = kb2 * 16 + hi * 8;
#pragma unroll
            for (int nf = 0; nf < 2; ++nf) {
                const float* vb = &Vl[k0 * 64 + nf * 32 + c];
                union { unsigned int u[4]; bf16x8 v; } V8;
                V8.u[0] = pk2bf(vb[0 * 64], vb[1 * 64]);
                V8.u[1] = pk2bf(vb[2 * 64], vb[3 * 64]);
                V8.u[2] = pk2bf(vb[4 * 64], vb[5 * 64]);
                V8.u[3] = pk2bf(vb[6 * 64], vb[7 * 64]);
                oacc[nf] = __builtin_amdgcn_mfma_f32_32x32x16_bf16(A.v, V8.v, oacc[nf], 0, 0, 0);
            }
        }
    }

    // ---- store O with deferred 1/rowsum broadcast from q-owner lanes ----
#pragma unroll
    for (int reg = 0; reg < 16; ++reg) {
        const int qr = (reg & 3) + 8 * (reg >> 2) + 4 * hi;
        const float rv = __shfl(rinv, qr);
#pragma unroll
        for (int nf = 0; nf < 2; ++nf) {
            Op[(size_t)(qbase + qr) * DM + nf * 32 + c] = oacc[nf][reg] * rv;
        }
    }
}

extern "C" void kernel_launch(void* const* d_in, const int* in_sizes, int n_in,
                              void* d_out, int out_size, void* d_ws, size_t ws_size,
                              hipStream_t stream) {
    const float* q1 = (const float*)d_in[0];
    const float* k1 = (const float*)d_in[1];
    const float* v1 = (const float*)d_in[2];
    const float* q2 = (const float*)d_in[3];
    const float* k2 = (const float*)d_in[4];
    const float* v2 = (const float*)d_in[5];

    const int B = 8;
    const int nw1 = in_sizes[0] / (B * DM * WSZ);   // 32
    const int nw2 = in_sizes[3] / (B * DM * WSZ);   // 16

    float* o1 = (float*)d_out;
    float* o2 = o1 + (size_t)in_sizes[0];

    const int nblk1 = B * nw1 * NH;                 // 2048
    const int nblk2 = B * nw2 * NH;                 // 1024

    wattn_kernel<<<dim3(nblk1 + nblk2), dim3(256), 0, stream>>>(
        q1, k1, v1, o1, nw1, q2, k2, v2, o2, nw2, nblk1);
}